// Round 3
// baseline (300.103 us; speedup 1.0000x reference)
//
#include <hip/hip_runtime.h>
#include <stdint.h>

#define Bn 256
#define Tn 50
#define Mn 20
#define En 128
#define G3 384
#define MT 64        // bt-rows per block in GEMM kernel
#define LDA 132      // padded LDS row stride (floats): bank-stride 4, conflict-free

__device__ __forceinline__ float sigmoidf(float x) {
    return 1.0f / (1.0f + __expf(-x));
}
__device__ __forceinline__ float tanh_safe(float a) {
    float ax = fabsf(a);
    float e2 = __expf(-2.0f * ax);
    return copysignf((1.0f - e2) / (1.0f + e2), a);
}

// ---------------------------------------------------------------------------
// Kernel 1: fused basket-mean gather + tiled GEMM  xg = ub @ W_ih^T + b_ih
// grid = 400 blocks: 200 M-tiles x 2 N-halves; 256 threads.
// LDS: A[64][132] + B[64][132] = 67.6 KB -> 2 blocks/CU.
// Thread tile 4x4: per k-float4: 8 ds_read_b128 -> 64 fma (VALU-bound).
// ---------------------------------------------------------------------------
__global__ __launch_bounds__(256, 2) void gather_gemm_kernel(
    const int*   __restrict__ item_ids,      // [B*T*M]
    const int*   __restrict__ basket_sizes,  // [B*T]
    const float* __restrict__ emb,           // [(V+2)*E]
    const float* __restrict__ W_ih,          // [3E*E]
    const float* __restrict__ b_ih,          // [3E]
    float* __restrict__ xg)                  // [B*T*3E] ws
{
    __shared__ float A[MT][LDA];
    __shared__ float Bt[64][LDA];

    const int tid  = threadIdx.x;
    const int mt   = blockIdx.x >> 1;     // M-tile index (0..199)
    const int half = blockIdx.x & 1;      // N half (cols 0..191 / 192..383)
    const int row0 = mt * MT;

    // ---- gather + mean into A: thread = (row r=tid>>2, seg tid&3 of 32 floats)
    {
        const int r   = tid >> 2;
        const int seg = tid & 3;
        const int bt  = row0 + r;
        const int* ids = item_ids + (size_t)bt * Mn;
        const float* ebase = emb + (size_t)seg * 32;
        float4 a0 = {0,0,0,0}, a1 = {0,0,0,0}, a2 = {0,0,0,0}, a3 = {0,0,0,0};
        float4 a4 = {0,0,0,0}, a5 = {0,0,0,0}, a6 = {0,0,0,0}, a7 = {0,0,0,0};
        #pragma unroll
        for (int m = 0; m < Mn; ++m) {
            const float4* e4 = (const float4*)(ebase + (size_t)ids[m] * En);
            float4 v0 = e4[0], v1 = e4[1], v2 = e4[2], v3 = e4[3];
            float4 v4 = e4[4], v5 = e4[5], v6 = e4[6], v7 = e4[7];
            a0.x+=v0.x; a0.y+=v0.y; a0.z+=v0.z; a0.w+=v0.w;
            a1.x+=v1.x; a1.y+=v1.y; a1.z+=v1.z; a1.w+=v1.w;
            a2.x+=v2.x; a2.y+=v2.y; a2.z+=v2.z; a2.w+=v2.w;
            a3.x+=v3.x; a3.y+=v3.y; a3.z+=v3.z; a3.w+=v3.w;
            a4.x+=v4.x; a4.y+=v4.y; a4.z+=v4.z; a4.w+=v4.w;
            a5.x+=v5.x; a5.y+=v5.y; a5.z+=v5.z; a5.w+=v5.w;
            a6.x+=v6.x; a6.y+=v6.y; a6.z+=v6.z; a6.w+=v6.w;
            a7.x+=v7.x; a7.y+=v7.y; a7.z+=v7.z; a7.w+=v7.w;
        }
        const float inv = 1.0f / (float)basket_sizes[bt];
        float4* dst = (float4*)&A[r][seg * 32];
        dst[0] = make_float4(a0.x*inv,a0.y*inv,a0.z*inv,a0.w*inv);
        dst[1] = make_float4(a1.x*inv,a1.y*inv,a1.z*inv,a1.w*inv);
        dst[2] = make_float4(a2.x*inv,a2.y*inv,a2.z*inv,a2.w*inv);
        dst[3] = make_float4(a3.x*inv,a3.y*inv,a3.z*inv,a3.w*inv);
        dst[4] = make_float4(a4.x*inv,a4.y*inv,a4.z*inv,a4.w*inv);
        dst[5] = make_float4(a5.x*inv,a5.y*inv,a5.z*inv,a5.w*inv);
        dst[6] = make_float4(a6.x*inv,a6.y*inv,a6.z*inv,a6.w*inv);
        dst[7] = make_float4(a7.x*inv,a7.y*inv,a7.z*inv,a7.w*inv);
    }
    __syncthreads();

    const int tx = tid & 15;      // N dir
    const int ty = tid >> 4;      // M dir

    #pragma unroll
    for (int nc = 0; nc < 3; ++nc) {
        const int col0 = half * 192 + nc * 64;
        // load B chunk (W_ih rows col0..col0+63)
        {
            const int r   = tid >> 2;
            const int seg = tid & 3;
            const float4* src = (const float4*)(W_ih + (size_t)(col0 + r) * En + seg * 32);
            float4* dst = (float4*)&Bt[r][seg * 32];
            #pragma unroll
            for (int c = 0; c < 8; ++c) dst[c] = src[c];
        }
        __syncthreads();

        float acc[4][4];
        #pragma unroll
        for (int i = 0; i < 4; ++i)
            #pragma unroll
            for (int u = 0; u < 4; ++u) acc[i][u] = 0.0f;

        #pragma unroll 4
        for (int k4 = 0; k4 < 32; ++k4) {
            float4 a0 = *(const float4*)&A[ty +  0][k4*4];
            float4 a1 = *(const float4*)&A[ty + 16][k4*4];
            float4 a2 = *(const float4*)&A[ty + 32][k4*4];
            float4 a3 = *(const float4*)&A[ty + 48][k4*4];
            float4 b0 = *(const float4*)&Bt[tx +  0][k4*4];
            float4 b1 = *(const float4*)&Bt[tx + 16][k4*4];
            float4 b2 = *(const float4*)&Bt[tx + 32][k4*4];
            float4 b3 = *(const float4*)&Bt[tx + 48][k4*4];
            const float4 av[4] = {a0, a1, a2, a3};
            const float4 bv[4] = {b0, b1, b2, b3};
            #pragma unroll
            for (int i = 0; i < 4; ++i)
                #pragma unroll
                for (int u = 0; u < 4; ++u) {
                    acc[i][u] = fmaf(av[i].x, bv[u].x, acc[i][u]);
                    acc[i][u] = fmaf(av[i].y, bv[u].y, acc[i][u]);
                    acc[i][u] = fmaf(av[i].z, bv[u].z, acc[i][u]);
                    acc[i][u] = fmaf(av[i].w, bv[u].w, acc[i][u]);
                }
        }

        float bias[4];
        #pragma unroll
        for (int u = 0; u < 4; ++u) bias[u] = b_ih[col0 + tx + 16*u];

        #pragma unroll
        for (int i = 0; i < 4; ++i) {
            const size_t rowoff = (size_t)(row0 + ty + 16*i) * G3;
            #pragma unroll
            for (int u = 0; u < 4; ++u)
                xg[rowoff + col0 + tx + 16*u] = acc[i][u] + bias[u];
        }
        __syncthreads();   // protect Bt before next chunk load
    }
}

// ---------------------------------------------------------------------------
// Kernel 2: sequential GRU. 256 blocks (one per batch row) x 128 threads.
// Thread j holds W_hh rows j (r), 128+j (z), 256+j (n): 96 float4 in VGPRs.
// Each ds_read_b128 of h feeds 12 fma; all 3 gates computed in-thread, so no
// hg exchange through LDS and a single barrier pair per step.
// ---------------------------------------------------------------------------
__global__ __launch_bounds__(128, 1) void gru_kernel(
    const int*   __restrict__ lengths,   // [B]
    const float* __restrict__ W_hh,      // [3E*E]
    const float* __restrict__ b_hh,      // [3E]
    const float* __restrict__ h0,        // [B*E]
    const float* __restrict__ xg,        // [B*T*3E]
    float* __restrict__ out_dyn,         // [B*T*E]
    float* __restrict__ out_h)           // [B*E]
{
    __shared__ float hs[En];
    const int j = threadIdx.x;
    const int b = blockIdx.x;

    float4 wr[32], wz[32], wn[32];
    {
        const float4* p0 = (const float4*)(W_hh + (size_t)j * En);
        const float4* p1 = (const float4*)(W_hh + (size_t)(En + j) * En);
        const float4* p2 = (const float4*)(W_hh + (size_t)(2*En + j) * En);
        #pragma unroll
        for (int c = 0; c < 32; ++c) { wr[c] = p0[c]; wz[c] = p1[c]; wn[c] = p2[c]; }
    }
    const float br = b_hh[j], bz = b_hh[En + j], bn = b_hh[2*En + j];
    hs[j] = h0[(size_t)b * En + j];
    const int len = lengths[b];
    const float* xgb = xg + (size_t)b * Tn * G3;
    float* outb = out_dyn + (size_t)b * Tn * En;
    __syncthreads();

    for (int t = 0; t < len; ++t) {
        // prefetch xg for this step (hidden behind the dot product)
        const float xr = xgb[t*G3 + j];
        const float xz = xgb[t*G3 + En + j];
        const float xn = xgb[t*G3 + 2*En + j];

        const float4* h4 = (const float4*)hs;
        float ar0=0.f, ar1=0.f, az0=0.f, az1=0.f, an0=0.f, an1=0.f;
        #pragma unroll
        for (int c = 0; c < 32; c += 2) {
            float4 hA = h4[c], hB = h4[c+1];
            ar0 = fmaf(wr[c].x,hA.x,ar0); ar0 = fmaf(wr[c].y,hA.y,ar0);
            ar0 = fmaf(wr[c].z,hA.z,ar0); ar0 = fmaf(wr[c].w,hA.w,ar0);
            az0 = fmaf(wz[c].x,hA.x,az0); az0 = fmaf(wz[c].y,hA.y,az0);
            az0 = fmaf(wz[c].z,hA.z,az0); az0 = fmaf(wz[c].w,hA.w,az0);
            an0 = fmaf(wn[c].x,hA.x,an0); an0 = fmaf(wn[c].y,hA.y,an0);
            an0 = fmaf(wn[c].z,hA.z,an0); an0 = fmaf(wn[c].w,hA.w,an0);
            ar1 = fmaf(wr[c+1].x,hB.x,ar1); ar1 = fmaf(wr[c+1].y,hB.y,ar1);
            ar1 = fmaf(wr[c+1].z,hB.z,ar1); ar1 = fmaf(wr[c+1].w,hB.w,ar1);
            az1 = fmaf(wz[c+1].x,hB.x,az1); az1 = fmaf(wz[c+1].y,hB.y,az1);
            az1 = fmaf(wz[c+1].z,hB.z,az1); az1 = fmaf(wz[c+1].w,hB.w,az1);
            an1 = fmaf(wn[c+1].x,hB.x,an1); an1 = fmaf(wn[c+1].y,hB.y,an1);
            an1 = fmaf(wn[c+1].z,hB.z,an1); an1 = fmaf(wn[c+1].w,hB.w,an1);
        }
        const float hold = hs[j];
        const float r = sigmoidf(xr + br + ar0 + ar1);
        const float z = sigmoidf(xz + bz + az0 + az1);
        const float n = tanh_safe(xn + r * (bn + an0 + an1));
        const float hnew = (1.0f - z) * n + z * hold;
        __syncthreads();              // all reads of old h complete
        hs[j] = hnew;
        outb[t*En + j] = hnew;
        __syncthreads();              // new h visible
    }
    for (int t = len; t < Tn; ++t) outb[t*En + j] = 0.0f;
    out_h[(size_t)b * En + j] = hs[j];
}

extern "C" void kernel_launch(void* const* d_in, const int* in_sizes, int n_in,
                              void* d_out, int out_size, void* d_ws, size_t ws_size,
                              hipStream_t stream) {
    const int*   item_ids     = (const int*)d_in[0];
    const int*   basket_sizes = (const int*)d_in[1];
    const int*   lengths      = (const int*)d_in[2];
    const float* emb          = (const float*)d_in[3];
    const float* W_ih         = (const float*)d_in[4];
    const float* W_hh         = (const float*)d_in[5];
    const float* b_ih         = (const float*)d_in[6];
    const float* b_hh         = (const float*)d_in[7];
    const float* h0           = (const float*)d_in[8];
    float* out = (float*)d_out;
    float* xg  = (float*)d_ws;    // 12800*384*4 = 19.7 MB

    gather_gemm_kernel<<<400, 256, 0, stream>>>(
        item_ids, basket_sizes, emb, W_ih, b_ih, xg);
    gru_kernel<<<Bn, 128, 0, stream>>>(
        lengths, W_hh, b_hh, h0, xg, out, out + (size_t)Bn * Tn * En);
}

// Round 4
// 188.195 us; speedup vs baseline: 1.5946x; 1.5946x over previous
//
#include <hip/hip_runtime.h>
#include <stdint.h>

#define Bn 256
#define Tn 50
#define Mn 20
#define En 128
#define G3 384
#define MT 64
#define LDA 132

__device__ __forceinline__ float sigmoidf(float x) {
    return 1.0f / (1.0f + __expf(-x));
}
__device__ __forceinline__ float tanh_safe(float a) {
    float ax = fabsf(a);
    float e2 = __expf(-2.0f * ax);
    return copysignf((1.0f - e2) / (1.0f + e2), a);
}

// ---------------------------------------------------------------------------
// Kernel 1: basket-mean gather -> ub [B*T][128]  (stored in d_out region)
// 1600 blocks x 256 thr; 32-lane group per bt row; fully coalesced.
// ---------------------------------------------------------------------------
__global__ __launch_bounds__(256) void gather_kernel(
    const int*   __restrict__ item_ids,
    const int*   __restrict__ basket_sizes,
    const float* __restrict__ emb,
    float* __restrict__ ub)
{
    const int bt   = blockIdx.x * 8 + (threadIdx.x >> 5);
    const int lane = threadIdx.x & 31;
    const int* ids = item_ids + (size_t)bt * Mn;
    float ax = 0.f, ay = 0.f, az = 0.f, aw = 0.f;
    #pragma unroll
    for (int m = 0; m < Mn; ++m) {
        const float4 v = *(const float4*)(emb + (size_t)ids[m] * En + lane * 4);
        ax += v.x; ay += v.y; az += v.z; aw += v.w;
    }
    const float inv = 1.0f / (float)basket_sizes[bt];
    *(float4*)(ub + (size_t)bt * En + lane * 4) =
        make_float4(ax * inv, ay * inv, az * inv, aw * inv);
}

// ---------------------------------------------------------------------------
// Kernel 2: xg = ub @ W_ih^T + b_ih.  400 blocks (200 M-tiles x 2 N-halves).
// 4x4 thread tile; A-load now a plain coalesced read of ub.
// ---------------------------------------------------------------------------
__global__ __launch_bounds__(256, 2) void gemm_kernel(
    const float* __restrict__ ub,
    const float* __restrict__ W_ih,
    const float* __restrict__ b_ih,
    float* __restrict__ xg)
{
    __shared__ float A[MT][LDA];
    __shared__ float Bt[64][LDA];

    const int tid  = threadIdx.x;
    const int mt   = blockIdx.x >> 1;
    const int half = blockIdx.x & 1;
    const int row0 = mt * MT;

    {
        const int r = tid >> 2, seg = tid & 3;
        const float4* src = (const float4*)(ub + (size_t)(row0 + r) * En + seg * 32);
        float4* dst = (float4*)&A[r][seg * 32];
        #pragma unroll
        for (int c = 0; c < 8; ++c) dst[c] = src[c];
    }
    __syncthreads();

    const int tx = tid & 15;
    const int ty = tid >> 4;

    #pragma unroll
    for (int nc = 0; nc < 3; ++nc) {
        const int col0 = half * 192 + nc * 64;
        {
            const int r = tid >> 2, seg = tid & 3;
            const float4* src = (const float4*)(W_ih + (size_t)(col0 + r) * En + seg * 32);
            float4* dst = (float4*)&Bt[r][seg * 32];
            #pragma unroll
            for (int c = 0; c < 8; ++c) dst[c] = src[c];
        }
        __syncthreads();

        float acc[4][4];
        #pragma unroll
        for (int i = 0; i < 4; ++i)
            #pragma unroll
            for (int u = 0; u < 4; ++u) acc[i][u] = 0.0f;

        #pragma unroll 4
        for (int k4 = 0; k4 < 32; ++k4) {
            const float4 av[4] = {
                *(const float4*)&A[ty +  0][k4*4], *(const float4*)&A[ty + 16][k4*4],
                *(const float4*)&A[ty + 32][k4*4], *(const float4*)&A[ty + 48][k4*4]};
            const float4 bv[4] = {
                *(const float4*)&Bt[tx +  0][k4*4], *(const float4*)&Bt[tx + 16][k4*4],
                *(const float4*)&Bt[tx + 32][k4*4], *(const float4*)&Bt[tx + 48][k4*4]};
            #pragma unroll
            for (int i = 0; i < 4; ++i)
                #pragma unroll
                for (int u = 0; u < 4; ++u) {
                    acc[i][u] = fmaf(av[i].x, bv[u].x, acc[i][u]);
                    acc[i][u] = fmaf(av[i].y, bv[u].y, acc[i][u]);
                    acc[i][u] = fmaf(av[i].z, bv[u].z, acc[i][u]);
                    acc[i][u] = fmaf(av[i].w, bv[u].w, acc[i][u]);
                }
        }

        float bias[4];
        #pragma unroll
        for (int u = 0; u < 4; ++u) bias[u] = b_ih[col0 + tx + 16*u];
        #pragma unroll
        for (int i = 0; i < 4; ++i) {
            const size_t rowoff = (size_t)(row0 + ty + 16*i) * G3;
            #pragma unroll
            for (int u = 0; u < 4; ++u)
                xg[rowoff + col0 + tx + 16*u] = acc[i][u] + bias[u];
        }
        __syncthreads();
    }
}

// ---------------------------------------------------------------------------
// Kernel 3: sequential GRU. 256 blocks x 256 threads.
// Decomposition: (j2 in [0,64)) x (q in [0,4) K-split). Thread holds 6 weight
// row-slices of 32 floats = 192 VGPRs (no spill). Partials via 6KB LDS.
// ---------------------------------------------------------------------------
__global__ __launch_bounds__(256, 1) void gru_kernel(
    const int*   __restrict__ lengths,
    const float* __restrict__ W_hh,
    const float* __restrict__ b_hh,
    const float* __restrict__ h0,
    const float* __restrict__ xg,
    float* __restrict__ out_dyn,
    float* __restrict__ out_h)
{
    __shared__ float hs[En];
    __shared__ float red[4][3][En];   // [q][gate][j]

    const int tid = threadIdx.x;
    const int b   = blockIdx.x;
    const int q   = tid >> 6;     // wave-uniform
    const int j2  = tid & 63;

    // weights: rows {g*128 + j2 + 64a : g=0..2, a=0..1}, cols q*32..q*32+31
    float4 w[2][3][8];
    #pragma unroll
    for (int a = 0; a < 2; ++a)
        #pragma unroll
        for (int g = 0; g < 3; ++g) {
            const float4* p = (const float4*)(W_hh + ((size_t)(g*En + j2 + 64*a)) * En + q * 32);
            #pragma unroll
            for (int c = 0; c < 8; ++c) w[a][g][c] = p[c];
        }

    const int len = lengths[b];
    const float* xgb = xg + (size_t)b * Tn * G3;
    float* outb = out_dyn + (size_t)b * Tn * En;

    float xr = 0.f, xz = 0.f, xn = 0.f, br = 0.f, bz = 0.f, bn = 0.f;
    if (tid < En) {
        hs[tid] = h0[(size_t)b * En + tid];
        br = b_hh[tid]; bz = b_hh[En + tid]; bn = b_hh[2*En + tid];
        xr = xgb[tid];  xz = xgb[En + tid]; xn = xgb[2*En + tid];
    }
    __syncthreads();

    for (int t = 0; t < len; ++t) {
        // phase A: partial dot products (h read is full-wave broadcast)
        const float4* h4 = ((const float4*)hs) + q * 8;
        float a00=0.f,a01=0.f,a02=0.f,a10=0.f,a11=0.f,a12=0.f;
        #pragma unroll
        for (int c = 0; c < 8; ++c) {
            const float4 hv = h4[c];
            a00 = fmaf(w[0][0][c].x,hv.x,a00); a00 = fmaf(w[0][0][c].y,hv.y,a00);
            a00 = fmaf(w[0][0][c].z,hv.z,a00); a00 = fmaf(w[0][0][c].w,hv.w,a00);
            a01 = fmaf(w[0][1][c].x,hv.x,a01); a01 = fmaf(w[0][1][c].y,hv.y,a01);
            a01 = fmaf(w[0][1][c].z,hv.z,a01); a01 = fmaf(w[0][1][c].w,hv.w,a01);
            a02 = fmaf(w[0][2][c].x,hv.x,a02); a02 = fmaf(w[0][2][c].y,hv.y,a02);
            a02 = fmaf(w[0][2][c].z,hv.z,a02); a02 = fmaf(w[0][2][c].w,hv.w,a02);
            a10 = fmaf(w[1][0][c].x,hv.x,a10); a10 = fmaf(w[1][0][c].y,hv.y,a10);
            a10 = fmaf(w[1][0][c].z,hv.z,a10); a10 = fmaf(w[1][0][c].w,hv.w,a10);
            a11 = fmaf(w[1][1][c].x,hv.x,a11); a11 = fmaf(w[1][1][c].y,hv.y,a11);
            a11 = fmaf(w[1][1][c].z,hv.z,a11); a11 = fmaf(w[1][1][c].w,hv.w,a11);
            a12 = fmaf(w[1][2][c].x,hv.x,a12); a12 = fmaf(w[1][2][c].y,hv.y,a12);
            a12 = fmaf(w[1][2][c].z,hv.z,a12); a12 = fmaf(w[1][2][c].w,hv.w,a12);
        }
        red[q][0][j2]    = a00; red[q][1][j2]    = a01; red[q][2][j2]    = a02;
        red[q][0][j2+64] = a10; red[q][1][j2+64] = a11; red[q][2][j2+64] = a12;

        // prefetch next step's xg (hidden behind barrier + phase B)
        float nxr = 0.f, nxz = 0.f, nxn = 0.f;
        if (tid < En) {
            const int tn = (t + 1 < len) ? t + 1 : t;
            nxr = xgb[tn*G3 + tid];
            nxz = xgb[tn*G3 + En + tid];
            nxn = xgb[tn*G3 + 2*En + tid];
        }
        __syncthreads();

        // phase B: reduce + gates (first 2 waves)
        if (tid < En) {
            const float ar = red[0][0][tid]+red[1][0][tid]+red[2][0][tid]+red[3][0][tid];
            const float az = red[0][1][tid]+red[1][1][tid]+red[2][1][tid]+red[3][1][tid];
            const float an = red[0][2][tid]+red[1][2][tid]+red[2][2][tid]+red[3][2][tid];
            const float r = sigmoidf(xr + br + ar);
            const float z = sigmoidf(xz + bz + az);
            const float n = tanh_safe(xn + r * (bn + an));
            const float hold = hs[tid];
            const float hnew = (1.0f - z) * n + z * hold;
            hs[tid] = hnew;
            outb[t*En + tid] = hnew;
            xr = nxr; xz = nxz; xn = nxn;
        }
        __syncthreads();
    }

    if (tid < En) {
        for (int t = len; t < Tn; ++t) outb[t*En + tid] = 0.0f;
        out_h[(size_t)b * En + tid] = hs[tid];
    }
}

extern "C" void kernel_launch(void* const* d_in, const int* in_sizes, int n_in,
                              void* d_out, int out_size, void* d_ws, size_t ws_size,
                              hipStream_t stream) {
    const int*   item_ids     = (const int*)d_in[0];
    const int*   basket_sizes = (const int*)d_in[1];
    const int*   lengths      = (const int*)d_in[2];
    const float* emb          = (const float*)d_in[3];
    const float* W_ih         = (const float*)d_in[4];
    const float* W_hh         = (const float*)d_in[5];
    const float* b_ih         = (const float*)d_in[6];
    const float* b_hh         = (const float*)d_in[7];
    const float* h0           = (const float*)d_in[8];
    float* out = (float*)d_out;
    float* xg  = (float*)d_ws;             // 19.7 MB
    float* ub  = out;                      // reuse out_dyn region as ub scratch;
                                           // consumed by gemm, then overwritten by gru

    gather_kernel<<<(Bn * Tn) / 8, 256, 0, stream>>>(item_ids, basket_sizes, emb, ub);
    gemm_kernel<<<400, 256, 0, stream>>>(ub, W_ih, b_ih, xg);
    gru_kernel<<<Bn, 256, 0, stream>>>(
        lengths, W_hh, b_hh, h0, xg, out, out + (size_t)Bn * Tn * En);
}